// Round 20
// baseline (174.679 us; speedup 1.0000x reference)
//
#include <hip/hip_runtime.h>
#include <hip/hip_fp16.h>
#include <math.h>

#define BB 2
#define SS 2048
#define DD 1024
#define HH 16
#define MTOT (BB*SS)   // 4096

typedef _Float16 f16;
typedef _Float16 f16x4 __attribute__((ext_vector_type(4)));
typedef _Float16 f16x8 __attribute__((ext_vector_type(8)));
typedef float    f32x4 __attribute__((ext_vector_type(4)));

// logit scale folded into K at its producing GEMM: 1/sqrt(64) * log2(e)
#define KSCALE 0.1803368801111204f

__device__ __forceinline__ float silu_f(float x) {
    return x / (1.0f + __expf(-x));
}

// async global->LDS, 16B per lane. lds base wave-uniform; HW writes lane l at
// lds + l*16. Global src per-lane (carries the swizzle / gather).
__device__ __forceinline__ void gload16(void* lds, const void* g) {
    __builtin_amdgcn_global_load_lds(
        (const __attribute__((address_space(1))) unsigned*)g,
        (__attribute__((address_space(3))) unsigned*)lds, 16, 0, 0);
}

// ---------------------------------------------------------------------------
// Fused prep: [0,6144) fp32->f16 convert of q,k,v; [6144,7936) weight
// transpose+convert (7 weights x 256 tiles); [7936,7938) mask scan.
// uidx[total..SS) zero-filled so gather reads are always initialized.
// ---------------------------------------------------------------------------
__global__ __launch_bounds__(256) void prep(
    const float* __restrict__ q, const float* __restrict__ k, const float* __restrict__ v,
    f16* __restrict__ x0, f16* __restrict__ x1, f16* __restrict__ x2,
    const float* __restrict__ w0, const float* __restrict__ w1, const float* __restrict__ w2,
    const float* __restrict__ w3, const float* __restrict__ w4, const float* __restrict__ w5,
    const float* __restrict__ w6, f16* __restrict__ wt,
    const int* __restrict__ mask, int* __restrict__ uidx, int* __restrict__ ucnt)
{
    __shared__ float ts[64][65];
    const int gid = blockIdx.x;
    const int t = threadIdx.x;

    if (gid < 6144) {
        const int z = gid >> 11;
        const float* src = z == 0 ? q : z == 1 ? k : v;
        f16* dst = z == 0 ? x0 : z == 1 ? x1 : x2;
        const size_t i8 = ((size_t)(gid & 2047) * 256 + t) * 8;
        const float4 a = *(const float4*)(src + i8);
        const float4 b = *(const float4*)(src + i8 + 4);
        f16x8 h = {(f16)a.x,(f16)a.y,(f16)a.z,(f16)a.w,(f16)b.x,(f16)b.y,(f16)b.z,(f16)b.w};
        *(f16x8*)(dst + i8) = h;
    } else if (gid < 7936) {
        const int w = gid - 6144;
        const int z = w >> 8;
        const int rem = w & 255;
        const int bn = (rem & 15) << 6, bk = (rem >> 4) << 6;
        const float* src;
        switch (z) {
            case 0: src = w0; break; case 1: src = w1; break;
            case 2: src = w2; break; case 3: src = w3; break;
            case 4: src = w4; break; case 5: src = w5; break;
            default: src = w6; break;
        }
        f16* dst = wt + ((size_t)z << 20);
        #pragma unroll
        for (int i = 0; i < 4; ++i) {
            const int fid = t + (i << 8);
            const int r = fid >> 4, c4 = (fid & 15) << 2;
            const float4 v4 = *(const float4*)(src + (size_t)(bk + r) * 1024 + bn + c4);
            ts[r][c4 + 0] = v4.x; ts[r][c4 + 1] = v4.y;
            ts[r][c4 + 2] = v4.z; ts[r][c4 + 3] = v4.w;
        }
        __syncthreads();
        #pragma unroll
        for (int i = 0; i < 4; ++i) {
            const int fid = t + (i << 8);
            const int nr = fid >> 4, k4 = (fid & 15) << 2;
            f16x4 h = { (f16)ts[k4 + 0][nr], (f16)ts[k4 + 1][nr],
                        (f16)ts[k4 + 2][nr], (f16)ts[k4 + 3][nr] };
            *(f16x4*)(dst + (size_t)(bn + nr) * 1024 + bk + k4) = h;
        }
    } else {
        int* ps = (int*)ts;
        const int b = gid - 7936;
        int f[8]; int cnt = 0;
        const int base = b * SS + t * 8;
        #pragma unroll
        for (int j = 0; j < 8; ++j) { f[j] = (mask[base + j] == 0); cnt += f[j]; }
        ps[t] = cnt;
        __syncthreads();
        for (int off = 1; off < 256; off <<= 1) {
            const int pv = (t >= off) ? ps[t - off] : 0;
            __syncthreads();
            ps[t] += pv;
            __syncthreads();
        }
        int pos = ps[t] - cnt;
        #pragma unroll
        for (int j = 0; j < 8; ++j)
            if (f[j]) uidx[b * SS + pos++] = t * 8 + j;
        const int total = ps[255];
        const int pad = (total + 63) & ~63;
        for (int j = total + t; j < SS; j += 256) uidx[b * SS + j] = 0;
        if (t == 0) { ucnt[b * 2] = total; ucnt[b * 2 + 1] = pad; }
    }
}

// ---------------------------------------------------------------------------
// Depthwise conv K=3 SAME, f16 in/out, fp32 math, 8 ch/thread. grid (2048,3).
// ---------------------------------------------------------------------------
__global__ __launch_bounds__(256) void dwconv3g(
    const f16* __restrict__ p0, const f16* __restrict__ p1, const f16* __restrict__ p2,
    const float* __restrict__ w0, const float* __restrict__ w1, const float* __restrict__ w2,
    f16* __restrict__ o0, f16* __restrict__ o1, f16* __restrict__ o2)
{
    const int z = blockIdx.y;
    const f16* x = z == 0 ? p0 : z == 1 ? p1 : p2;
    const float* dw = z == 0 ? w0 : z == 1 ? w1 : w2;
    f16* y = z == 0 ? o0 : z == 1 ? o1 : o2;
    const size_t i8 = ((size_t)blockIdx.x * 256 + threadIdx.x) * 8;
    const int c = (int)(i8 % DD);
    const int s = (int)((i8 / DD) % SS);
    const f16x8 xc = *(const f16x8*)(x + i8);
    float acc[8];
    #pragma unroll
    for (int j = 0; j < 8; ++j) acc[j] = (float)xc[j] * dw[DD + c + j];
    if (s > 0) {
        const f16x8 xm = *(const f16x8*)(x + i8 - DD);
        #pragma unroll
        for (int j = 0; j < 8; ++j) acc[j] = fmaf((float)xm[j], dw[c + j], acc[j]);
    }
    if (s < SS - 1) {
        const f16x8 xp = *(const f16x8*)(x + i8 + DD);
        #pragma unroll
        for (int j = 0; j < 8; ++j) acc[j] = fmaf((float)xp[j], dw[2 * DD + c + j], acc[j]);
    }
    f16x8 o;
    #pragma unroll
    for (int j = 0; j < 8; ++j) o[j] = (f16)acc[j];
    *(f16x8*)(y + i8) = o;
}

struct GArg { const f16* A; const f16* W; const float* b; void* C; float scale; int gather; };

// ---------------------------------------------------------------------------
// 128x128-tile GEMM [R3-proven]. Used for the output dense (grid (8,32,1)):
// 256 blocks = 1/CU.
// ---------------------------------------------------------------------------
template<int OUTF32>
__global__ __launch_bounds__(256) void gemm_f16(GArg g0, GArg g1, GArg g2)
{
    __shared__ f16 As[128 * 64];
    __shared__ f16 Bs[128 * 64];

    const GArg ga = blockIdx.z == 0 ? g0 : blockIdx.z == 1 ? g1 : g2;
    const int t = threadIdx.x, l = t & 63, wv = t >> 6;
    const int lr = l & 15, lg = l >> 4;
    const int wr = wv >> 1, wc = wv & 1;

    const int bid = blockIdx.y * 8 + blockIdx.x;
    const int sw = (bid & 7) * 32 + (bid >> 3);
    const int brow = (sw >> 3) << 7, bcol = (sw & 7) << 7;

    const int srow = l >> 3;
    const int schk = (l & 7) ^ (l >> 3);
    const f16* Abase = ga.A + (size_t)(brow + wv * 32 + srow) * 1024 + schk * 8;
    const f16* Bbase = ga.W + (size_t)(bcol + wv * 32 + srow) * 1024 + schk * 8;

    f32x4 acc[4][4];
    #pragma unroll
    for (int m = 0; m < 4; ++m)
        #pragma unroll
        for (int n = 0; n < 4; ++n) acc[m][n] = (f32x4){0.f, 0.f, 0.f, 0.f};

    for (int kt = 0; kt < 16; ++kt) {
        const int k0 = kt << 6;
        #pragma unroll
        for (int j = 0; j < 4; ++j) {
            gload16(As + (wv * 4 + j) * 512, Abase + (size_t)j * 8 * 1024 + k0);
            gload16(Bs + (wv * 4 + j) * 512, Bbase + (size_t)j * 8 * 1024 + k0);
        }
        __syncthreads();

        #pragma unroll
        for (int kk = 0; kk < 2; ++kk) {
            f16x8 af[4], bf[4];
            #pragma unroll
            for (int m = 0; m < 4; ++m) {
                const int row = (wr << 6) + (m << 4) + lr;
                const int off = row * 128 + ((((kk << 6) | (lg << 4))) ^ ((lr & 7) << 4));
                af[m] = *(const f16x8*)((const char*)As + off);
            }
            #pragma unroll
            for (int n = 0; n < 4; ++n) {
                const int row = (wc << 6) + (n << 4) + lr;
                const int off = row * 128 + ((((kk << 6) | (lg << 4))) ^ ((lr & 7) << 4));
                bf[n] = *(const f16x8*)((const char*)Bs + off);
            }
            #pragma unroll
            for (int m = 0; m < 4; ++m)
                #pragma unroll
                for (int n = 0; n < 4; ++n)
                    acc[m][n] = __builtin_amdgcn_mfma_f32_16x16x32_f16(af[m], bf[n], acc[m][n], 0, 0, 0);
        }
        __syncthreads();
    }

    float bv[4];
    #pragma unroll
    for (int n = 0; n < 4; ++n) bv[n] = ga.b[bcol + (wc << 6) + (n << 4) + lr];
    #pragma unroll
    for (int m = 0; m < 4; ++m)
        #pragma unroll
        for (int n = 0; n < 4; ++n)
            #pragma unroll
            for (int i = 0; i < 4; ++i) {
                const int row = brow + (wr << 6) + (m << 4) + (lg << 2) + i;
                const int col = bcol + (wc << 6) + (n << 4) + lr;
                const float o = silu_f(acc[m][n][i] + bv[n]) * ga.scale;
                if (OUTF32) ((float*)ga.C)[(size_t)row * 1024 + col] = o;
                else        ((f16*)ga.C)[(size_t)row * 1024 + col] = (f16)o;
            }
}

// ---------------------------------------------------------------------------
// 256x128-tile GEMM, 8 waves (4M x 2N). [R13/R15-proven] Optional A-row
// gather (compaction). grid (8, 16, nz), 512 thr.
// ---------------------------------------------------------------------------
template<int OUTF32>
__global__ __launch_bounds__(512) void gemm256(GArg g0, GArg g1, GArg g2,
    const int* __restrict__ uidx, const int* __restrict__ ucnt)
{
    __shared__ f16 As[256 * 64];   // 32KB
    __shared__ f16 Bs[128 * 64];   // 16KB

    const GArg ga = blockIdx.z == 0 ? g0 : blockIdx.z == 1 ? g1 : g2;
    const int t = threadIdx.x, l = t & 63, wv = t >> 6;   // wv 0..7
    const int lr = l & 15, lg = l >> 4;
    const int wm = wv >> 1, wn = wv & 1;                  // 4M x 2N

    const int bid = blockIdx.y * 8 + blockIdx.x;
    const int sw = (bid & 7) * 16 + (bid >> 3);
    const int brow = (sw >> 3) << 8;
    const int bcol = (sw & 7) << 7;

    const int b = brow >> 11;                             // batch of this panel
    if (ga.gather) {
        if ((brow & 2047) >= ucnt[b * 2 + 1]) return;     // whole panel beyond pad
    }

    const int srow = l >> 3;
    const int schk = (l & 7) ^ (l >> 3);

    const f16* Aptr[4];
    #pragma unroll
    for (int j = 0; j < 4; ++j) {
        int r = (brow & 2047) + wv * 32 + j * 8 + srow;
        if (ga.gather) r = uidx[b * SS + r];              // zero-filled past total
        Aptr[j] = ga.A + ((size_t)(b << 11) + r) * 1024 + schk * 8;
    }
    const f16* Bbase = ga.W + (size_t)(bcol + wv * 16 + srow) * 1024 + schk * 8;

    f32x4 acc[4][4];
    #pragma unroll
    for (int m = 0; m < 4; ++m)
        #pragma unroll
        for (int n = 0; n < 4; ++n) acc[m][n] = (f32x4){0.f, 0.f, 0.f, 0.f};

    for (int kt = 0; kt < 16; ++kt) {
        const int k0 = kt << 6;
        #pragma unroll
        for (int j = 0; j < 4; ++j)
            gload16(As + (wv * 4 + j) * 512, Aptr[j] + k0);
        #pragma unroll
        for (int j = 0; j < 2; ++j)
            gload16(Bs + (wv * 2 + j) * 512, Bbase + (size_t)j * 8 * 1024 + k0);
        __syncthreads();

        #pragma unroll
        for (int kk = 0; kk < 2; ++kk) {
            f16x8 af[4], bf[4];
            #pragma unroll
            for (int m = 0; m < 4; ++m) {
                const int row = (wm << 6) + (m << 4) + lr;
                const int off = row * 128 + ((((kk << 6) | (lg << 4))) ^ ((lr & 7) << 4));
                af[m] = *(const f16x8*)((const char*)As + off);
            }
            #pragma unroll
            for (int n = 0; n < 4; ++n) {
                const int row = (wn << 6) + (n << 4) + lr;
                const int off = row * 128 + ((((kk << 6) | (lg << 4))) ^ ((lr & 7) << 4));
                bf[n] = *(const f16x8*)((const char*)Bs + off);
            }
            #pragma unroll
            for (int m = 0; m < 4; ++m)
                #pragma unroll
                for (int n = 0; n < 4; ++n)
                    acc[m][n] = __builtin_amdgcn_mfma_f32_16x16x32_f16(af[m], bf[n], acc[m][n], 0, 0, 0);
        }
        __syncthreads();
    }

    float bv[4];
    #pragma unroll
    for (int n = 0; n < 4; ++n) bv[n] = ga.b[bcol + (wn << 6) + (n << 4) + lr];
    #pragma unroll
    for (int m = 0; m < 4; ++m)
        #pragma unroll
        for (int n = 0; n < 4; ++n)
            #pragma unroll
            for (int i = 0; i < 4; ++i) {
                const int row = brow + (wm << 6) + (m << 4) + (lg << 2) + i;
                const int col = bcol + (wn << 6) + (n << 4) + lr;
                const float o = silu_f(acc[m][n][i] + bv[n]) * ga.scale;
                if (OUTF32) ((float*)ga.C)[(size_t)row * 1024 + col] = o;
                else        ((f16*)ga.C)[(size_t)row * 1024 + col] = (f16)o;
            }
}

// ---------------------------------------------------------------------------
// Flash attention over COMPACT K/V. Swapped-operand [R14/R15/R17-proven],
// 128 q-rows/block (8 waves x 16), 128 keys per barrier-pair, lazy
// defer-max. V-transpose staging spread across all 8 waves (wave w stages
// tile w>>2; halves the stage critical path vs 4-wave double duty).
// grid 512, 512 thr. LDS 48KB.
// ---------------------------------------------------------------------------
__global__ __launch_bounds__(512) void attn_f16(
    const f16* __restrict__ Q, const f16* __restrict__ Kf,
    const f16* __restrict__ Vf, const int* __restrict__ ucnt,
    f16* __restrict__ O)
{
    __shared__ f16 Ks[2 * 64 * 64];    // [tile][key][d], swizzled (16KB)
    __shared__ f16 Vt[2 * 64 * 64];    // [tile][d][key], swizzled (16KB)
    __shared__ f16 Pw[8 * 16 * 64];    // per-wave P^T rows=q (16KB)

    const int t = threadIdx.x;
    const int l = t & 63, wv = t >> 6;          // wv in 0..7
    const int lr = l & 15, lg = l >> 4;

    const int bid = blockIdx.x;                 // 0..511
    const int sw = (bid & 7) * 64 + (bid >> 3); // bijective XCD swizzle
    const int qb = (sw & 15) << 7;              // 16 q-blocks of 128 rows
    const int h  = (sw >> 4) & 15;
    const int b  = sw >> 8;

    const int cnt = ucnt[b * 2];
    const int pad = ucnt[b * 2 + 1];

    const int srow = l >> 3;
    const int schk = (l & 7) ^ (l >> 3);

    // V-transpose mapping: wave w stages tile w>>2 (8-wave spread)
    const int th    = t & 255;
    const int vtile = t >> 8;        // 0 or 1
    const int bkv = (th & 15) << 2;  // key base
    const int bnv = (th >> 4) << 2;  // d base

    const size_t bbase = (size_t)b * SS;
    const size_t qrow = bbase + qb + (wv << 4) + lr;   // lane's own q-row
    const f16x8 aq0 = *(const f16x8*)(Q + qrow * DD + h * 64 + (lg << 3));
    const f16x8 aq1 = *(const f16x8*)(Q + qrow * DD + h * 64 + 32 + (lg << 3));

    float m_s = -1e30f, l_s = 0.f;
    f32x4 acc[4];                      // acc[n][i] = O[q=lr][d = 16n+4lg+i]
    #pragma unroll
    for (int n = 0; n < 4; ++n) acc[n] = (f32x4){0.f, 0.f, 0.f, 0.f};

    const int rdswz = (lr & 7) << 4;
    const int poff = (wv << 11) + lr * 128;

// One 64-key tile TB (LDS byte base TB*8192) at key offset KT.
#define PROCESS(TB, KT) do {                                                  \
    const int kb = (TB) * 8192;                                               \
    f16x8 bk0[4], bk1[4];                                                     \
    _Pragma("unroll")                                                         \
    for (int n = 0; n < 4; ++n) {                                             \
        const int row = (n << 4) + lr;                                        \
        bk0[n] = *(const f16x8*)((const char*)Ks + kb + row * 128 + (((lg << 4)) ^ rdswz));        \
        bk1[n] = *(const f16x8*)((const char*)Ks + kb + row * 128 + (((64) | (lg << 4)) ^ rdswz)); \
    }                                                                         \
    const bool full = ((KT) + 64 <= cnt);                                     \
    /* S^T = mfma(A=K, B=Q): lane holds S[key=16n+4lg+i][q=lr] */             \
    f32x4 s[4];                                                               \
    __builtin_amdgcn_s_setprio(1);                                            \
    _Pragma("unroll")                                                         \
    for (int n = 0; n < 4; ++n) {                                             \
        f32x4 z = (f32x4){0.f, 0.f, 0.f, 0.f};                                \
        z = __builtin_amdgcn_mfma_f32_16x16x32_f16(bk0[n], aq0, z, 0, 0, 0);  \
        z = __builtin_amdgcn_mfma_f32_16x16x32_f16(bk1[n], aq1, z, 0, 0, 0);  \
        if (full) {                                                           \
            _Pragma("unroll")                                                 \
            for (int i = 0; i < 4; ++i) s[n][i] = z[i];                       \
        } else {                                                              \
            _Pragma("unroll")                                                 \
            for (int i = 0; i < 4; ++i) {                                     \
                const bool valid = ((KT) + (n << 4) + (lg << 2) + i) < cnt;   \
                s[n][i] = valid ? z[i] : -1e30f;                              \
            }                                                                 \
        }                                                                     \
    }                                                                         \
    __builtin_amdgcn_s_setprio(0);                                            \
    float pm = s[0][0];                                                       \
    _Pragma("unroll")                                                         \
    for (int n = 0; n < 4; ++n)                                               \
        _Pragma("unroll")                                                     \
        for (int i = 0; i < 4; ++i) pm = fmaxf(pm, s[n][i]);                  \
    if (!__all(pm - m_s <= 8.0f)) {    /* rare: row-reduce + rescale */       \
        float pr = pm;                                                        \
        pr = fmaxf(pr, __shfl_xor(pr, 16));                                   \
        pr = fmaxf(pr, __shfl_xor(pr, 32));                                   \
        const float mn = fmaxf(m_s, pr);                                      \
        const float sc = exp2f(m_s - mn);                                     \
        m_s = mn;                                                             \
        l_s *= sc;                                                            \
        _Pragma("unroll")                                                     \
        for (int n = 0; n < 4; ++n)                                           \
            _Pragma("unroll")                                                 \
            for (int i = 0; i < 4; ++i) acc[n][i] *= sc;                      \
    }                                                                         \
    _Pragma("unroll")                                                         \
    for (int n = 0; n < 4; ++n) {                                             \
        f16x4 p4;                                                             \
        _Pragma("unroll")                                                     \
        for (int i = 0; i < 4; ++i) {                                         \
            const float p = exp2f(s[n][i] - m_s);   /* bounded by 2^8 */      \
            l_s += p;                                                         \
            p4[i] = (f16)p;                                                   \
        }                                                                     \
        const int off = poff + (((n << 5) | (lg << 3)) ^ rdswz);              \
        *(f16x4*)((char*)Pw + off) = p4;                                      \
    }                                                                         \
    {                                                                         \
        const f16x8 pb0 = *(const f16x8*)((const char*)Pw + poff + (((lg << 4)) ^ rdswz));        \
        const f16x8 pb1 = *(const f16x8*)((const char*)Pw + poff + (((64) | (lg << 4)) ^ rdswz)); \
        __builtin_amdgcn_s_setprio(1);                                        \
        _Pragma("unroll")                                                     \
        for (int n = 0; n < 4; ++n) {                                         \
            const int row = (n << 4) + lr;                                    \
            const f16x8 av0 = *(const f16x8*)((const char*)Vt + kb + row * 128 + (((lg << 4)) ^ rdswz));        \
            const f16x8 av1 = *(const f16x8*)((const char*)Vt + kb + row * 128 + (((64) | (lg << 4)) ^ rdswz)); \
            acc[n] = __builtin_amdgcn_mfma_f32_16x16x32_f16(av0, pb0, acc[n], 0, 0, 0);  \
            acc[n] = __builtin_amdgcn_mfma_f32_16x16x32_f16(av1, pb1, acc[n], 0, 0, 0);  \
        }                                                                     \
        __builtin_amdgcn_s_setprio(0);                                        \
    }                                                                         \
} while (0)

    for (int kt = 0; kt < pad; kt += 128) {
        const bool two = (kt + 64) < pad;
        // ---- stage K for both tiles (direct compact rows) ----
        gload16(Ks + wv * 512,
                Kf + (bbase + kt + wv * 8 + srow) * DD + h * 64 + schk * 8);
        if (two)
            gload16(Ks + 4096 + wv * 512,
                    Kf + (bbase + kt + 64 + wv * 8 + srow) * DD + h * 64 + schk * 8);
        // ---- stage V transposed: wave w -> tile w>>2 (8-wave spread) ----
        if (vtile == 0 || two) {
            f16x4 vl[4];
            #pragma unroll
            for (int r = 0; r < 4; ++r)
                vl[r] = *(const f16x4*)(Vf + (bbase + kt + vtile * 64 + bkv + r) * DD + h * 64 + bnv);
            #pragma unroll
            for (int j = 0; j < 4; ++j) {
                f16x4 h4 = { vl[0][j], vl[1][j], vl[2][j], vl[3][j] };
                const int row = bnv + j;
                const int off = vtile * 8192 + row * 128 + ((bkv * 2) ^ ((row & 7) << 4));
                *(f16x4*)((char*)Vt + off) = h4;
            }
        }
        __syncthreads();

        PROCESS(0, kt);
        if (two) PROCESS(1, kt + 64);

        __syncthreads();
    }
#undef PROCESS

    // epilogue: sum over the 4 lanes sharing q=lr, divide, vector store
    l_s += __shfl_xor(l_s, 16);
    l_s += __shfl_xor(l_s, 32);
    const float inv = 1.0f / l_s;
    const size_t orow = bbase + qb + (wv << 4) + lr;
    #pragma unroll
    for (int n = 0; n < 4; ++n) {
        f16x4 o4;
        #pragma unroll
        for (int i = 0; i < 4; ++i) o4[i] = (f16)(acc[n][i] * inv);
        *(f16x4*)(O + orow * DD + h * 64 + (n << 4) + (lg << 2)) = o4;
    }
}

// ---------------------------------------------------------------------------
extern "C" void kernel_launch(void* const* d_in, const int* in_sizes, int n_in,
                              void* d_out, int out_size, void* d_ws, size_t ws_size,
                              hipStream_t stream) {
    const float* v    = (const float*)d_in[0];
    const float* k    = (const float*)d_in[1];
    const float* q    = (const float*)d_in[2];
    const int*   mask = (const int*)  d_in[3];
    const float* wq_w = (const float*)d_in[4];
    const float* wq_b = (const float*)d_in[5];
    const float* wk_w = (const float*)d_in[6];
    const float* wk_b = (const float*)d_in[7];
    const float* wv_w = (const float*)d_in[8];
    const float* wv_b = (const float*)d_in[9];
    const float* dwq  = (const float*)d_in[10];
    const float* pwq  = (const float*)d_in[11];
    const float* bq   = (const float*)d_in[12];
    const float* dwk  = (const float*)d_in[13];
    const float* pwk  = (const float*)d_in[14];
    const float* bk   = (const float*)d_in[15];
    const float* dwv  = (const float*)d_in[16];
    const float* pwv  = (const float*)d_in[17];
    const float* bv   = (const float*)d_in[18];
    const float* wo_w = (const float*)d_in[19];
    const float* wo_b = (const float*)d_in[20];
    float* out = (float*)d_out;

    const size_t NE = (size_t)MTOT * DD;        // 4M elems
    f16* wt = (f16*)d_ws;                       // 7 x 1M f16 (14MB)
    f16* x0 = wt + 7 * (size_t)(1 << 20);       // 3 x 4M f16 (24MB)
    f16* x1 = x0 + NE;
    f16* x2 = x1 + NE;
    f16* p0 = x2 + NE;                          // 3 x 4M f16 (24MB)
    f16* p1 = p0 + NE;
    f16* p2 = p1 + NE;
    f16* ao = p2 + NE;                          // 4M f16 (8MB)
    int* uidx = (int*)(ao + NE);                // 4096 ints
    int* ucnt = uidx + MTOT;                    // 4 ints

    f16* wtq = wt,              *wtk = wt + (1u<<20), *wtv = wt + 2*(1u<<20);
    f16* wpq = wt + 3*(1u<<20), *wpk = wt + 4*(1u<<20), *wpv = wt + 5*(1u<<20);
    f16* wto = wt + 6*(1u<<20);

    // 1. fused prep: cvt q/k/v + transpose 7 weights + mask scan
    prep<<<dim3(7938), 256, 0, stream>>>(q, k, v, x0, x1, x2,
        wq_w, wk_w, wv_w, pwq, pwk, pwv, wo_w, wt, mask, uidx, ucnt);
    // 2. projection GEMMs (batched): x* -> p*
    gemm256<0><<<dim3(8, 16, 3), 512, 0, stream>>>(
        GArg{x0, wtq, wq_b, p0, 1.0f, 0}, GArg{x1, wtk, wk_b, p1, 1.0f, 0},
        GArg{x2, wtv, wv_b, p2, 1.0f, 0}, uidx, ucnt);
    // 3. depthwise convs (batched): p* -> x*
    dwconv3g<<<dim3(2048, 3), 256, 0, stream>>>(p0, p1, p2, dwq, dwk, dwv, x0, x1, x2);
    // 4. pointwise GEMMs; K/V gathered+compacted, K pre-scaled: x* -> p*
    gemm256<0><<<dim3(8, 16, 3), 512, 0, stream>>>(
        GArg{x0, wpq, bq, p0, 1.0f, 0}, GArg{x1, wpk, bk, p1, KSCALE, 1},
        GArg{x2, wpv, bv, p2, 1.0f, 1}, uidx, ucnt);
    // 5. flash attention (swapped-operand, compact K/V, 128 q-rows) -> ao
    attn_f16<<<dim3(512), 512, 0, stream>>>(p0, p1, p2, ucnt, ao);
    // 6. output dense (128x128 tile, 256 blocks = 1/CU, fp32 out) -> d_out
    gemm_f16<1><<<dim3(8, 32, 1), 256, 0, stream>>>(
        GArg{ao, wto, wo_b, out, 1.0f, 0}, GArg{ao, wto, wo_b, out, 1.0f, 0},
        GArg{ao, wto, wo_b, out, 1.0f, 0});
}

// Round 21
// 173.366 us; speedup vs baseline: 1.0076x; 1.0076x over previous
//
#include <hip/hip_runtime.h>
#include <hip/hip_fp16.h>
#include <math.h>

#define BB 2
#define SS 2048
#define DD 1024
#define HH 16
#define MTOT (BB*SS)   // 4096

typedef _Float16 f16;
typedef _Float16 f16x4 __attribute__((ext_vector_type(4)));
typedef _Float16 f16x8 __attribute__((ext_vector_type(8)));
typedef float    f32x4 __attribute__((ext_vector_type(4)));

// logit scale folded into K at its producing GEMM: 1/sqrt(64) * log2(e)
#define KSCALE 0.1803368801111204f

__device__ __forceinline__ float silu_f(float x) {
    return x / (1.0f + __expf(-x));
}

// async global->LDS, 16B per lane. lds base wave-uniform; HW writes lane l at
// lds + l*16. Global src per-lane (carries the swizzle / gather).
__device__ __forceinline__ void gload16(void* lds, const void* g) {
    __builtin_amdgcn_global_load_lds(
        (const __attribute__((address_space(1))) unsigned*)g,
        (__attribute__((address_space(3))) unsigned*)lds, 16, 0, 0);
}

// ---------------------------------------------------------------------------
// Fused prep: [0,6144) fp32->f16 convert of q,k,v; [6144,7936) weight
// transpose+convert (7 weights x 256 tiles); [7936,7938) mask scan.
// uidx[total..SS) zero-filled so gather reads are always initialized.
// ---------------------------------------------------------------------------
__global__ __launch_bounds__(256) void prep(
    const float* __restrict__ q, const float* __restrict__ k, const float* __restrict__ v,
    f16* __restrict__ x0, f16* __restrict__ x1, f16* __restrict__ x2,
    const float* __restrict__ w0, const float* __restrict__ w1, const float* __restrict__ w2,
    const float* __restrict__ w3, const float* __restrict__ w4, const float* __restrict__ w5,
    const float* __restrict__ w6, f16* __restrict__ wt,
    const int* __restrict__ mask, int* __restrict__ uidx, int* __restrict__ ucnt)
{
    __shared__ float ts[64][65];
    const int gid = blockIdx.x;
    const int t = threadIdx.x;

    if (gid < 6144) {
        const int z = gid >> 11;
        const float* src = z == 0 ? q : z == 1 ? k : v;
        f16* dst = z == 0 ? x0 : z == 1 ? x1 : x2;
        const size_t i8 = ((size_t)(gid & 2047) * 256 + t) * 8;
        const float4 a = *(const float4*)(src + i8);
        const float4 b = *(const float4*)(src + i8 + 4);
        f16x8 h = {(f16)a.x,(f16)a.y,(f16)a.z,(f16)a.w,(f16)b.x,(f16)b.y,(f16)b.z,(f16)b.w};
        *(f16x8*)(dst + i8) = h;
    } else if (gid < 7936) {
        const int w = gid - 6144;
        const int z = w >> 8;
        const int rem = w & 255;
        const int bn = (rem & 15) << 6, bk = (rem >> 4) << 6;
        const float* src;
        switch (z) {
            case 0: src = w0; break; case 1: src = w1; break;
            case 2: src = w2; break; case 3: src = w3; break;
            case 4: src = w4; break; case 5: src = w5; break;
            default: src = w6; break;
        }
        f16* dst = wt + ((size_t)z << 20);
        #pragma unroll
        for (int i = 0; i < 4; ++i) {
            const int fid = t + (i << 8);
            const int r = fid >> 4, c4 = (fid & 15) << 2;
            const float4 v4 = *(const float4*)(src + (size_t)(bk + r) * 1024 + bn + c4);
            ts[r][c4 + 0] = v4.x; ts[r][c4 + 1] = v4.y;
            ts[r][c4 + 2] = v4.z; ts[r][c4 + 3] = v4.w;
        }
        __syncthreads();
        #pragma unroll
        for (int i = 0; i < 4; ++i) {
            const int fid = t + (i << 8);
            const int nr = fid >> 4, k4 = (fid & 15) << 2;
            f16x4 h = { (f16)ts[k4 + 0][nr], (f16)ts[k4 + 1][nr],
                        (f16)ts[k4 + 2][nr], (f16)ts[k4 + 3][nr] };
            *(f16x4*)(dst + (size_t)(bn + nr) * 1024 + bk + k4) = h;
        }
    } else {
        int* ps = (int*)ts;
        const int b = gid - 7936;
        int f[8]; int cnt = 0;
        const int base = b * SS + t * 8;
        #pragma unroll
        for (int j = 0; j < 8; ++j) { f[j] = (mask[base + j] == 0); cnt += f[j]; }
        ps[t] = cnt;
        __syncthreads();
        for (int off = 1; off < 256; off <<= 1) {
            const int pv = (t >= off) ? ps[t - off] : 0;
            __syncthreads();
            ps[t] += pv;
            __syncthreads();
        }
        int pos = ps[t] - cnt;
        #pragma unroll
        for (int j = 0; j < 8; ++j)
            if (f[j]) uidx[b * SS + pos++] = t * 8 + j;
        const int total = ps[255];
        const int pad = (total + 63) & ~63;
        for (int j = total + t; j < SS; j += 256) uidx[b * SS + j] = 0;
        if (t == 0) { ucnt[b * 2] = total; ucnt[b * 2 + 1] = pad; }
    }
}

// ---------------------------------------------------------------------------
// Depthwise conv K=3 SAME, f16 in/out, fp32 math, 8 ch/thread. grid (2048,3).
// ---------------------------------------------------------------------------
__global__ __launch_bounds__(256) void dwconv3g(
    const f16* __restrict__ p0, const f16* __restrict__ p1, const f16* __restrict__ p2,
    const float* __restrict__ w0, const float* __restrict__ w1, const float* __restrict__ w2,
    f16* __restrict__ o0, f16* __restrict__ o1, f16* __restrict__ o2)
{
    const int z = blockIdx.y;
    const f16* x = z == 0 ? p0 : z == 1 ? p1 : p2;
    const float* dw = z == 0 ? w0 : z == 1 ? w1 : w2;
    f16* y = z == 0 ? o0 : z == 1 ? o1 : o2;
    const size_t i8 = ((size_t)blockIdx.x * 256 + threadIdx.x) * 8;
    const int c = (int)(i8 % DD);
    const int s = (int)((i8 / DD) % SS);
    const f16x8 xc = *(const f16x8*)(x + i8);
    float acc[8];
    #pragma unroll
    for (int j = 0; j < 8; ++j) acc[j] = (float)xc[j] * dw[DD + c + j];
    if (s > 0) {
        const f16x8 xm = *(const f16x8*)(x + i8 - DD);
        #pragma unroll
        for (int j = 0; j < 8; ++j) acc[j] = fmaf((float)xm[j], dw[c + j], acc[j]);
    }
    if (s < SS - 1) {
        const f16x8 xp = *(const f16x8*)(x + i8 + DD);
        #pragma unroll
        for (int j = 0; j < 8; ++j) acc[j] = fmaf((float)xp[j], dw[2 * DD + c + j], acc[j]);
    }
    f16x8 o;
    #pragma unroll
    for (int j = 0; j < 8; ++j) o[j] = (f16)acc[j];
    *(f16x8*)(y + i8) = o;
}

struct GArg { const f16* A; const f16* W; const float* b; void* C; float scale; int gather; };

// ---------------------------------------------------------------------------
// 128x128-tile GEMM [R3-proven]. Used for the output dense (grid (8,32,1)):
// 256 blocks = 1/CU.
// ---------------------------------------------------------------------------
template<int OUTF32>
__global__ __launch_bounds__(256) void gemm_f16(GArg g0, GArg g1, GArg g2)
{
    __shared__ f16 As[128 * 64];
    __shared__ f16 Bs[128 * 64];

    const GArg ga = blockIdx.z == 0 ? g0 : blockIdx.z == 1 ? g1 : g2;
    const int t = threadIdx.x, l = t & 63, wv = t >> 6;
    const int lr = l & 15, lg = l >> 4;
    const int wr = wv >> 1, wc = wv & 1;

    const int bid = blockIdx.y * 8 + blockIdx.x;
    const int sw = (bid & 7) * 32 + (bid >> 3);
    const int brow = (sw >> 3) << 7, bcol = (sw & 7) << 7;

    const int srow = l >> 3;
    const int schk = (l & 7) ^ (l >> 3);
    const f16* Abase = ga.A + (size_t)(brow + wv * 32 + srow) * 1024 + schk * 8;
    const f16* Bbase = ga.W + (size_t)(bcol + wv * 32 + srow) * 1024 + schk * 8;

    f32x4 acc[4][4];
    #pragma unroll
    for (int m = 0; m < 4; ++m)
        #pragma unroll
        for (int n = 0; n < 4; ++n) acc[m][n] = (f32x4){0.f, 0.f, 0.f, 0.f};

    for (int kt = 0; kt < 16; ++kt) {
        const int k0 = kt << 6;
        #pragma unroll
        for (int j = 0; j < 4; ++j) {
            gload16(As + (wv * 4 + j) * 512, Abase + (size_t)j * 8 * 1024 + k0);
            gload16(Bs + (wv * 4 + j) * 512, Bbase + (size_t)j * 8 * 1024 + k0);
        }
        __syncthreads();

        #pragma unroll
        for (int kk = 0; kk < 2; ++kk) {
            f16x8 af[4], bf[4];
            #pragma unroll
            for (int m = 0; m < 4; ++m) {
                const int row = (wr << 6) + (m << 4) + lr;
                const int off = row * 128 + ((((kk << 6) | (lg << 4))) ^ ((lr & 7) << 4));
                af[m] = *(const f16x8*)((const char*)As + off);
            }
            #pragma unroll
            for (int n = 0; n < 4; ++n) {
                const int row = (wc << 6) + (n << 4) + lr;
                const int off = row * 128 + ((((kk << 6) | (lg << 4))) ^ ((lr & 7) << 4));
                bf[n] = *(const f16x8*)((const char*)Bs + off);
            }
            #pragma unroll
            for (int m = 0; m < 4; ++m)
                #pragma unroll
                for (int n = 0; n < 4; ++n)
                    acc[m][n] = __builtin_amdgcn_mfma_f32_16x16x32_f16(af[m], bf[n], acc[m][n], 0, 0, 0);
        }
        __syncthreads();
    }

    float bv[4];
    #pragma unroll
    for (int n = 0; n < 4; ++n) bv[n] = ga.b[bcol + (wc << 6) + (n << 4) + lr];
    #pragma unroll
    for (int m = 0; m < 4; ++m)
        #pragma unroll
        for (int n = 0; n < 4; ++n)
            #pragma unroll
            for (int i = 0; i < 4; ++i) {
                const int row = brow + (wr << 6) + (m << 4) + (lg << 2) + i;
                const int col = bcol + (wc << 6) + (n << 4) + lr;
                const float o = silu_f(acc[m][n][i] + bv[n]) * ga.scale;
                if (OUTF32) ((float*)ga.C)[(size_t)row * 1024 + col] = o;
                else        ((f16*)ga.C)[(size_t)row * 1024 + col] = (f16)o;
            }
}

// ---------------------------------------------------------------------------
// 256x128-tile GEMM, 8 waves (4M x 2N). [R13/R15-proven] Optional A-row
// gather (compaction). grid (8, 16, nz), 512 thr.
// ---------------------------------------------------------------------------
template<int OUTF32>
__global__ __launch_bounds__(512) void gemm256(GArg g0, GArg g1, GArg g2,
    const int* __restrict__ uidx, const int* __restrict__ ucnt)
{
    __shared__ f16 As[256 * 64];   // 32KB
    __shared__ f16 Bs[128 * 64];   // 16KB

    const GArg ga = blockIdx.z == 0 ? g0 : blockIdx.z == 1 ? g1 : g2;
    const int t = threadIdx.x, l = t & 63, wv = t >> 6;   // wv 0..7
    const int lr = l & 15, lg = l >> 4;
    const int wm = wv >> 1, wn = wv & 1;                  // 4M x 2N

    const int bid = blockIdx.y * 8 + blockIdx.x;
    const int sw = (bid & 7) * 16 + (bid >> 3);
    const int brow = (sw >> 3) << 8;
    const int bcol = (sw & 7) << 7;

    const int b = brow >> 11;                             // batch of this panel
    if (ga.gather) {
        if ((brow & 2047) >= ucnt[b * 2 + 1]) return;     // whole panel beyond pad
    }

    const int srow = l >> 3;
    const int schk = (l & 7) ^ (l >> 3);

    const f16* Aptr[4];
    #pragma unroll
    for (int j = 0; j < 4; ++j) {
        int r = (brow & 2047) + wv * 32 + j * 8 + srow;
        if (ga.gather) r = uidx[b * SS + r];              // zero-filled past total
        Aptr[j] = ga.A + ((size_t)(b << 11) + r) * 1024 + schk * 8;
    }
    const f16* Bbase = ga.W + (size_t)(bcol + wv * 16 + srow) * 1024 + schk * 8;

    f32x4 acc[4][4];
    #pragma unroll
    for (int m = 0; m < 4; ++m)
        #pragma unroll
        for (int n = 0; n < 4; ++n) acc[m][n] = (f32x4){0.f, 0.f, 0.f, 0.f};

    for (int kt = 0; kt < 16; ++kt) {
        const int k0 = kt << 6;
        #pragma unroll
        for (int j = 0; j < 4; ++j)
            gload16(As + (wv * 4 + j) * 512, Aptr[j] + k0);
        #pragma unroll
        for (int j = 0; j < 2; ++j)
            gload16(Bs + (wv * 2 + j) * 512, Bbase + (size_t)j * 8 * 1024 + k0);
        __syncthreads();

        #pragma unroll
        for (int kk = 0; kk < 2; ++kk) {
            f16x8 af[4], bf[4];
            #pragma unroll
            for (int m = 0; m < 4; ++m) {
                const int row = (wm << 6) + (m << 4) + lr;
                const int off = row * 128 + ((((kk << 6) | (lg << 4))) ^ ((lr & 7) << 4));
                af[m] = *(const f16x8*)((const char*)As + off);
            }
            #pragma unroll
            for (int n = 0; n < 4; ++n) {
                const int row = (wn << 6) + (n << 4) + lr;
                const int off = row * 128 + ((((kk << 6) | (lg << 4))) ^ ((lr & 7) << 4));
                bf[n] = *(const f16x8*)((const char*)Bs + off);
            }
            #pragma unroll
            for (int m = 0; m < 4; ++m)
                #pragma unroll
                for (int n = 0; n < 4; ++n)
                    acc[m][n] = __builtin_amdgcn_mfma_f32_16x16x32_f16(af[m], bf[n], acc[m][n], 0, 0, 0);
        }
        __syncthreads();
    }

    float bv[4];
    #pragma unroll
    for (int n = 0; n < 4; ++n) bv[n] = ga.b[bcol + (wn << 6) + (n << 4) + lr];
    #pragma unroll
    for (int m = 0; m < 4; ++m)
        #pragma unroll
        for (int n = 0; n < 4; ++n)
            #pragma unroll
            for (int i = 0; i < 4; ++i) {
                const int row = brow + (wm << 6) + (m << 4) + (lg << 2) + i;
                const int col = bcol + (wn << 6) + (n << 4) + lr;
                const float o = silu_f(acc[m][n][i] + bv[n]) * ga.scale;
                if (OUTF32) ((float*)ga.C)[(size_t)row * 1024 + col] = o;
                else        ((f16*)ga.C)[(size_t)row * 1024 + col] = (f16)o;
            }
}

// ---------------------------------------------------------------------------
// Flash attention over COMPACT K/V (no in-kernel gather). Swapped-operand
// form [R14/R15/R17-proven: 52 VGPR, 33% occ], 128 q-rows/block (8 waves x
// 16), 128 keys per barrier-pair, lazy defer-max. grid 512, 512 thr. LDS 48KB.
// ---------------------------------------------------------------------------
__global__ __launch_bounds__(512) void attn_f16(
    const f16* __restrict__ Q, const f16* __restrict__ Kf,
    const f16* __restrict__ Vf, const int* __restrict__ ucnt,
    f16* __restrict__ O)
{
    __shared__ f16 Ks[2 * 64 * 64];    // [tile][key][d], swizzled (16KB)
    __shared__ f16 Vt[2 * 64 * 64];    // [tile][d][key], swizzled (16KB)
    __shared__ f16 Pw[8 * 16 * 64];    // per-wave P^T rows=q (16KB)

    const int t = threadIdx.x;
    const int l = t & 63, wv = t >> 6;          // wv in 0..7
    const int lr = l & 15, lg = l >> 4;

    const int bid = blockIdx.x;                 // 0..511
    const int sw = (bid & 7) * 64 + (bid >> 3); // bijective XCD swizzle
    const int qb = (sw & 15) << 7;              // 16 q-blocks of 128 rows
    const int h  = (sw >> 4) & 15;
    const int b  = sw >> 8;

    const int cnt = ucnt[b * 2];
    const int pad = ucnt[b * 2 + 1];

    const int srow = l >> 3;
    const int schk = (l & 7) ^ (l >> 3);

    const int bkv = (t & 15) << 2;   // key base for V transpose (t<256 only)
    const int bnv = (t >> 4) << 2;   // d base (t<256 only)

    const size_t bbase = (size_t)b * SS;
    const size_t qrow = bbase + qb + (wv << 4) + lr;   // lane's own q-row
    const f16x8 aq0 = *(const f16x8*)(Q + qrow * DD + h * 64 + (lg << 3));
    const f16x8 aq1 = *(const f16x8*)(Q + qrow * DD + h * 64 + 32 + (lg << 3));

    float m_s = -1e30f, l_s = 0.f;
    f32x4 acc[4];                      // acc[n][i] = O[q=lr][d = 16n+4lg+i]
    #pragma unroll
    for (int n = 0; n < 4; ++n) acc[n] = (f32x4){0.f, 0.f, 0.f, 0.f};

    const int rdswz = (lr & 7) << 4;
    const int poff = (wv << 11) + lr * 128;

// One 64-key tile TB (LDS byte base TB*8192) at key offset KT.
#define PROCESS(TB, KT) do {                                                  \
    const int kb = (TB) * 8192;                                               \
    f16x8 bk0[4], bk1[4];                                                     \
    _Pragma("unroll")                                                         \
    for (int n = 0; n < 4; ++n) {                                             \
        const int row = (n << 4) + lr;                                        \
        bk0[n] = *(const f16x8*)((const char*)Ks + kb + row * 128 + (((lg << 4)) ^ rdswz));        \
        bk1[n] = *(const f16x8*)((const char*)Ks + kb + row * 128 + (((64) | (lg << 4)) ^ rdswz)); \
    }                                                                         \
    const bool full = ((KT) + 64 <= cnt);                                     \
    /* S^T = mfma(A=K, B=Q): lane holds S[key=16n+4lg+i][q=lr] */             \
    f32x4 s[4];                                                               \
    __builtin_amdgcn_s_setprio(1);                                            \
    _Pragma("unroll")                                                         \
    for (int n = 0; n < 4; ++n) {                                             \
        f32x4 z = (f32x4){0.f, 0.f, 0.f, 0.f};                                \
        z = __builtin_amdgcn_mfma_f32_16x16x32_f16(bk0[n], aq0, z, 0, 0, 0);  \
        z = __builtin_amdgcn_mfma_f32_16x16x32_f16(bk1[n], aq1, z, 0, 0, 0);  \
        if (full) {                                                           \
            _Pragma("unroll")                                                 \
            for (int i = 0; i < 4; ++i) s[n][i] = z[i];                       \
        } else {                                                              \
            _Pragma("unroll")                                                 \
            for (int i = 0; i < 4; ++i) {                                     \
                const bool valid = ((KT) + (n << 4) + (lg << 2) + i) < cnt;   \
                s[n][i] = valid ? z[i] : -1e30f;                              \
            }                                                                 \
        }                                                                     \
    }                                                                         \
    __builtin_amdgcn_s_setprio(0);                                            \
    float pm = s[0][0];                                                       \
    _Pragma("unroll")                                                         \
    for (int n = 0; n < 4; ++n)                                               \
        _Pragma("unroll")                                                     \
        for (int i = 0; i < 4; ++i) pm = fmaxf(pm, s[n][i]);                  \
    if (!__all(pm - m_s <= 8.0f)) {    /* rare: row-reduce + rescale */       \
        float pr = pm;                                                        \
        pr = fmaxf(pr, __shfl_xor(pr, 16));                                   \
        pr = fmaxf(pr, __shfl_xor(pr, 32));                                   \
        const float mn = fmaxf(m_s, pr);                                      \
        const float sc = exp2f(m_s - mn);                                     \
        m_s = mn;                                                             \
        l_s *= sc;                                                            \
        _Pragma("unroll")                                                     \
        for (int n = 0; n < 4; ++n)                                           \
            _Pragma("unroll")                                                 \
            for (int i = 0; i < 4; ++i) acc[n][i] *= sc;                      \
    }                                                                         \
    _Pragma("unroll")                                                         \
    for (int n = 0; n < 4; ++n) {                                             \
        f16x4 p4;                                                             \
        _Pragma("unroll")                                                     \
        for (int i = 0; i < 4; ++i) {                                         \
            const float p = exp2f(s[n][i] - m_s);   /* bounded by 2^8 */      \
            l_s += p;                                                         \
            p4[i] = (f16)p;                                                   \
        }                                                                     \
        const int off = poff + (((n << 5) | (lg << 3)) ^ rdswz);              \
        *(f16x4*)((char*)Pw + off) = p4;                                      \
    }                                                                         \
    {                                                                         \
        const f16x8 pb0 = *(const f16x8*)((const char*)Pw + poff + (((lg << 4)) ^ rdswz));        \
        const f16x8 pb1 = *(const f16x8*)((const char*)Pw + poff + (((64) | (lg << 4)) ^ rdswz)); \
        __builtin_amdgcn_s_setprio(1);                                        \
        _Pragma("unroll")                                                     \
        for (int n = 0; n < 4; ++n) {                                         \
            const int row = (n << 4) + lr;                                    \
            const f16x8 av0 = *(const f16x8*)((const char*)Vt + kb + row * 128 + (((lg << 4)) ^ rdswz));        \
            const f16x8 av1 = *(const f16x8*)((const char*)Vt + kb + row * 128 + (((64) | (lg << 4)) ^ rdswz)); \
            acc[n] = __builtin_amdgcn_mfma_f32_16x16x32_f16(av0, pb0, acc[n], 0, 0, 0);  \
            acc[n] = __builtin_amdgcn_mfma_f32_16x16x32_f16(av1, pb1, acc[n], 0, 0, 0);  \
        }                                                                     \
        __builtin_amdgcn_s_setprio(0);                                        \
    }                                                                         \
} while (0)

    for (int kt = 0; kt < pad; kt += 128) {
        const bool two = (kt + 64) < pad;
        // ---- stage K for both tiles (direct compact rows) ----
        gload16(Ks + wv * 512,
                Kf + (bbase + kt + wv * 8 + srow) * DD + h * 64 + schk * 8);
        if (two)
            gload16(Ks + 4096 + wv * 512,
                    Kf + (bbase + kt + 64 + wv * 8 + srow) * DD + h * 64 + schk * 8);
        // ---- stage V transposed for both tiles (first 4 waves) ----
        if (t < 256) {
            const int nhalf = two ? 2 : 1;
            for (int half = 0; half < nhalf; ++half) {
                f16x4 vl[4];
                #pragma unroll
                for (int r = 0; r < 4; ++r)
                    vl[r] = *(const f16x4*)(Vf + (bbase + kt + half * 64 + bkv + r) * DD + h * 64 + bnv);
                #pragma unroll
                for (int j = 0; j < 4; ++j) {
                    f16x4 h4 = { vl[0][j], vl[1][j], vl[2][j], vl[3][j] };
                    const int row = bnv + j;
                    const int off = half * 8192 + row * 128 + ((bkv * 2) ^ ((row & 7) << 4));
                    *(f16x4*)((char*)Vt + off) = h4;
                }
            }
        }
        __syncthreads();

        PROCESS(0, kt);
        if (two) PROCESS(1, kt + 64);

        __syncthreads();
    }
#undef PROCESS

    // epilogue: sum over the 4 lanes sharing q=lr, divide, vector store
    l_s += __shfl_xor(l_s, 16);
    l_s += __shfl_xor(l_s, 32);
    const float inv = 1.0f / l_s;
    const size_t orow = bbase + qb + (wv << 4) + lr;
    #pragma unroll
    for (int n = 0; n < 4; ++n) {
        f16x4 o4;
        #pragma unroll
        for (int i = 0; i < 4; ++i) o4[i] = (f16)(acc[n][i] * inv);
        *(f16x4*)(O + orow * DD + h * 64 + (n << 4) + (lg << 2)) = o4;
    }
}

// ---------------------------------------------------------------------------
extern "C" void kernel_launch(void* const* d_in, const int* in_sizes, int n_in,
                              void* d_out, int out_size, void* d_ws, size_t ws_size,
                              hipStream_t stream) {
    const float* v    = (const float*)d_in[0];
    const float* k    = (const float*)d_in[1];
    const float* q    = (const float*)d_in[2];
    const int*   mask = (const int*)  d_in[3];
    const float* wq_w = (const float*)d_in[4];
    const float* wq_b = (const float*)d_in[5];
    const float* wk_w = (const float*)d_in[6];
    const float* wk_b = (const float*)d_in[7];
    const float* wv_w = (const float*)d_in[8];
    const float* wv_b = (const float*)d_in[9];
    const float* dwq  = (const float*)d_in[10];
    const float* pwq  = (const float*)d_in[11];
    const float* bq   = (const float*)d_in[12];
    const float* dwk  = (const float*)d_in[13];
    const float* pwk  = (const float*)d_in[14];
    const float* bk   = (const float*)d_in[15];
    const float* dwv  = (const float*)d_in[16];
    const float* pwv  = (const float*)d_in[17];
    const float* bv   = (const float*)d_in[18];
    const float* wo_w = (const float*)d_in[19];
    const float* wo_b = (const float*)d_in[20];
    float* out = (float*)d_out;

    const size_t NE = (size_t)MTOT * DD;        // 4M elems
    f16* wt = (f16*)d_ws;                       // 7 x 1M f16 (14MB)
    f16* x0 = wt + 7 * (size_t)(1 << 20);       // 3 x 4M f16 (24MB)
    f16* x1 = x0 + NE;
    f16* x2 = x1 + NE;
    f16* p0 = x2 + NE;                          // 3 x 4M f16 (24MB)
    f16* p1 = p0 + NE;
    f16* p2 = p1 + NE;
    f16* ao = p2 + NE;                          // 4M f16 (8MB)
    int* uidx = (int*)(ao + NE);                // 4096 ints
    int* ucnt = uidx + MTOT;                    // 4 ints

    f16* wtq = wt,              *wtk = wt + (1u<<20), *wtv = wt + 2*(1u<<20);
    f16* wpq = wt + 3*(1u<<20), *wpk = wt + 4*(1u<<20), *wpv = wt + 5*(1u<<20);
    f16* wto = wt + 6*(1u<<20);

    // 1. fused prep: cvt q/k/v + transpose 7 weights + mask scan
    prep<<<dim3(7938), 256, 0, stream>>>(q, k, v, x0, x1, x2,
        wq_w, wk_w, wv_w, pwq, pwk, pwv, wo_w, wt, mask, uidx, ucnt);
    // 2. projection GEMMs (batched): x* -> p*
    gemm256<0><<<dim3(8, 16, 3), 512, 0, stream>>>(
        GArg{x0, wtq, wq_b, p0, 1.0f, 0}, GArg{x1, wtk, wk_b, p1, 1.0f, 0},
        GArg{x2, wtv, wv_b, p2, 1.0f, 0}, uidx, ucnt);
    // 3. depthwise convs (batched): p* -> x*
    dwconv3g<<<dim3(2048, 3), 256, 0, stream>>>(p0, p1, p2, dwq, dwk, dwv, x0, x1, x2);
    // 4. pointwise GEMMs; K/V gathered+compacted, K pre-scaled: x* -> p*
    gemm256<0><<<dim3(8, 16, 3), 512, 0, stream>>>(
        GArg{x0, wpq, bq, p0, 1.0f, 0}, GArg{x1, wpk, bk, p1, KSCALE, 1},
        GArg{x2, wpv, bv, p2, 1.0f, 1}, uidx, ucnt);
    // 5. flash attention (swapped-operand, compact K/V, 128 q-rows) -> ao
    attn_f16<<<dim3(512), 512, 0, stream>>>(p0, p1, p2, ucnt, ao);
    // 6. output dense (128x128 tile, 256 blocks = 1/CU, fp32 out) -> d_out
    gemm_f16<1><<<dim3(8, 32, 1), 256, 0, stream>>>(
        GArg{ao, wto, wo_b, out, 1.0f, 0}, GArg{ao, wto, wo_b, out, 1.0f, 0},
        GArg{ao, wto, wo_b, out, 1.0f, 0});
}